// Round 7
// baseline (2216.181 us; speedup 1.0000x reference)
//
#include <hip/hip_runtime.h>
#include <stdint.h>

// Word2MatEncoder: out[b] = prod_{s=0..63} table[sent[b,s]]  (28x28 fp32 chain)
//
// R12 = R11 with ONE change: inline-asm s_waitcnt fences -> builtin waitcnts.
// Poison analysis across R5..R11: every kernel containing
// asm volatile("s_waitcnt...":::"memory") exploded to 256 VGPR + GB-scale
// scratch traffic (R7/R8/R9/R11); every kernel using only
// __builtin_amdgcn_s_waitcnt + __syncthreads stayed at 144-160 VGPR
// (R5/R10). Mechanism: the "memory"-clobber asm blocks SROA of the A-array
// allocas (asm may read them) -> arrays demoted to scratch. The builtin is a
// backend-understood side-effecting intrinsic: machine-sched barrier for
// memory ops (ds_reads can't hoist above it) without poisoning alias info.
// Pipeline (unchanged from R11):
//  - lds[2] double buffer, STATIC indices (odd steps buf0, even buf1).
//  - steady step waits vmcnt(28): current matrix landed, next matrix's 28
//    loads stay in flight across the matmul. Peeled last step vmcnt(0).
//    In-loop vmem = ONLY dma loads (28/step) -> count exact.
//  - word-id byte-offset table in LDS (ds_read, lgkmcnt domain): no mid-loop
//    global pointer-chase to perturb the vmcnt pipeline.
//  - dma masked to 56 lanes -> CHUNK_F=224: 2x24.5KB + ptbl = 49.5KB LDS,
//    3 blocks/CU.
//  - single-wave blocks: no __syncthreads in the chain loop (combine keeps
//    R10's barriers; vmcnt=0 there so their drain is harmless).
// Waitcnt immediates (gfx9): vmcnt(28)=0x4F7C, lgkmcnt(0)=0xC07F,
// vmcnt(0)=0x0F70 (the R5-proven constant).
// fp32 throughout (no fp32 MFMA on CDNA4; bf16 error compounds over 63 muls).

#define D 28
#define EMB 784
#define SEQ 64
#define NITEMS 2048
#define LPI 7            // lanes per slot
#define SPW 8            // slots per wave (2 items x 4 segments)
#define RPL 4            // rows of the running product per lane
#define SEG_LEN 16
#define NCHUNK 28        // DMA chunks per matrix-set (1 row x 8 slots each)
#define CHUNK_F 224      // floats per chunk (56 lanes x 16B, lanes 56-63 off)
#define BUF_F (NCHUNK * CHUNK_F)  // 6272 floats = 25088 B per buffer

typedef __attribute__((address_space(3))) uint32_t lds_u32;
typedef const __attribute__((address_space(1))) uint32_t glb_u32;

// Stage one matrix per slot into an LDS buffer. glane = matrix base + rl*16B;
// chunk t pulls row t of each slot's matrix. Lanes 56-63 masked off; exec is
// never all-zero so each instruction still counts once in the wave's vmcnt:
// exactly 28 loads per dma_mat.
__device__ __forceinline__ void dma_mat(const float* glane, float* lds0,
                                        int lane) {
  if (lane < SPW * LPI) {
#pragma unroll
    for (int t = 0; t < NCHUNK; ++t)
      __builtin_amdgcn_global_load_lds((glb_u32*)(glane + t * D),
                                       (lds_u32*)(lds0 + t * CHUNK_F), 16, 0,
                                       0);
  }
}

// Cc = Aa @ M   (M staged in LDS at Bs with the chunk layout) -- R10 verbatim
// modulo CHUNK_F. Bank check: slot bases stride 28 floats, row stride 224
// (mod 32 == 0): 8 slots x 4 consecutive banks cover all 32 -- conflict-free.
#define MATMUL(Aa, Cc)                                                         \
  do {                                                                         \
    _Pragma("unroll") for (int k = 0; k < D; ++k) {                            \
      _Pragma("unroll") for (int jv = 0; jv < 7; ++jv) {                       \
        float4 m = *(const float4*)(Bs + k * CHUNK_F + 4 * jv);                \
        _Pragma("unroll") for (int r = 0; r < RPL; ++r) {                      \
          float a = Aa[r][k];                                                  \
          if (k == 0) {                                                        \
            Cc[r][4 * jv + 0] = a * m.x;                                       \
            Cc[r][4 * jv + 1] = a * m.y;                                       \
            Cc[r][4 * jv + 2] = a * m.z;                                       \
            Cc[r][4 * jv + 3] = a * m.w;                                       \
          } else {                                                             \
            Cc[r][4 * jv + 0] = fmaf(a, m.x, Cc[r][4 * jv + 0]);               \
            Cc[r][4 * jv + 1] = fmaf(a, m.y, Cc[r][4 * jv + 1]);               \
            Cc[r][4 * jv + 2] = fmaf(a, m.z, Cc[r][4 * jv + 2]);               \
            Cc[r][4 * jv + 3] = fmaf(a, m.w, Cc[r][4 * jv + 3]);               \
          }                                                                    \
        }                                                                      \
      }                                                                        \
    }                                                                          \
  } while (0)

// Pipelined step on buffer BI (static 0/1). At step top: outstanding = mat s
// (oldest 28, targeting buf BI) + mat s+1 (newest 28) -> vmcnt(28) retires
// mat s exactly. After compute + lgkm drain, restage THIS buffer with mat
// s+2 (address from the LDS pointer table).
#define STEP(Aa, Cc, BI)                                                       \
  do {                                                                         \
    __builtin_amdgcn_s_waitcnt(0x4F7C); /* vmcnt(28) */                        \
    const float* Bs = &lds[BI][0] + slot * (LPI * 4);                          \
    MATMUL(Aa, Cc);                                                            \
    __builtin_amdgcn_s_waitcnt(0xC07F); /* lgkmcnt(0): reads retired */        \
    if (s + 2 < SEG_LEN) {                                                     \
      uint32_t offn = ptbl[slot * SEG_LEN + s + 2];                            \
      dma_mat((const float*)((const char*)src + offn) + rl * 4, &lds[BI][0],   \
              lane);                                                           \
    }                                                                          \
    ++s;                                                                       \
  } while (0)

#define STEP_LAST(Aa, Cc, BI)                                                  \
  do {                                                                         \
    __builtin_amdgcn_s_waitcnt(0x0f70); /* vmcnt(0): last matrix landed */     \
    const float* Bs = &lds[BI][0] + slot * (LPI * 4);                          \
    MATMUL(Aa, Cc);                                                            \
  } while (0)

// Fused: chain 16 matrices per slot (pipelined), then combine each item's 4
// segment products in-block. One block = 2 items x 4 segments.
__global__ __launch_bounds__(64, 1) void fused_kernel(
    const float* __restrict__ src, const int* __restrict__ sent,
    float* __restrict__ dst, int ntask) {
  __shared__ __align__(16) float lds[2][BUF_F];
  __shared__ uint32_t ptbl[SPW * SEG_LEN];  // per-slot matrix byte offsets

  const int lane = threadIdx.x;
  int slot = lane / LPI;
  int rl = lane - slot * LPI;
  if (slot >= SPW) {  // lanes 56..63 mirror slot 7 (benign duplicates)
    slot = SPW - 1;
    rl = (lane - 56 < LPI) ? lane - 56 : LPI - 1;
  }
  int task = blockIdx.x * SPW + slot;
  if (task >= ntask) task = ntask - 1;

  const int item = task / 4;
  const int seg = task - item * 4;
  const int* sp = sent + item * SEQ + seg * SEG_LEN;

  // Load all 16 word-ids (64B-aligned) and publish byte offsets to LDS.
  // All lanes of a slot write identical values -- benign.
  const int4 w0 = ((const int4*)sp)[0];
  const int4 w1 = ((const int4*)sp)[1];
  const int4 w2 = ((const int4*)sp)[2];
  const int4 w3 = ((const int4*)sp)[3];
#define PW(i, v) ptbl[slot * SEG_LEN + (i)] = (uint32_t)(v) * (EMB * 4u)
  PW(0, w0.x);  PW(1, w0.y);  PW(2, w0.z);  PW(3, w0.w);
  PW(4, w1.x);  PW(5, w1.y);  PW(6, w1.z);  PW(7, w1.w);
  PW(8, w2.x);  PW(9, w2.y);  PW(10, w2.z); PW(11, w2.w);
  PW(12, w3.x); PW(13, w3.y); PW(14, w3.z); PW(15, w3.w);
#undef PW

  float A0[RPL][D], A1[RPL][D];

  // A0 = this lane's rows (rl*4 .. rl*4+3) of matrix 0 (direct loads).
  {
    const float* m0 =
        (const float*)((const char*)src + (uint32_t)w0.x * (EMB * 4u));
#pragma unroll
    for (int r = 0; r < RPL; ++r) {
      const float* rp = m0 + (rl * RPL + r) * D;
#pragma unroll
      for (int jv = 0; jv < 7; ++jv) {
        float4 v = *(const float4*)(rp + 4 * jv);
        A0[r][4 * jv + 0] = v.x;
        A0[r][4 * jv + 1] = v.y;
        A0[r][4 * jv + 2] = v.z;
        A0[r][4 * jv + 3] = v.w;
      }
    }
  }

  // Stage matrices 1 -> buf0 and 2 -> buf1 (56 loads in flight).
  dma_mat((const float*)((const char*)src + (uint32_t)w0.y * (EMB * 4u)) +
              rl * 4,
          &lds[0][0], lane);
  dma_mat((const float*)((const char*)src + (uint32_t)w0.z * (EMB * 4u)) +
              rl * 4,
          &lds[1][0], lane);

  int s = 1;
#pragma unroll 1
  for (int p = 0; p < (SEG_LEN - 2) / 2; ++p) {
    STEP(A0, A1, 0);  // odd steps consume buf0
    STEP(A1, A0, 1);  // even steps consume buf1
  }
  STEP_LAST(A0, A1, 0);  // step 15 -> segment product in A1

  // ---- fused combine: out[item] = ((P0@P1)@P2)@P3 (R10 verbatim) ----
  __syncthreads();  // chain's last LDS reads drained before overwrite

  // writers: slots 1,2,3 -> cols 0,28,56 ; slots 5,6,7 -> cols 84,112,140.
  // layout matches MATMUL's read: element [k][j] at lds[0][k*CHUNK_F+col+j].
  {
    const int wslot = (slot >= 4) ? slot - 4 : slot;  // 0..3 within item
    if (wslot != 0) {
      const int col = ((slot >= 4) ? 3 : 0) * D + (wslot - 1) * D;
      float* wp = &lds[0][0] + col;
#pragma unroll
      for (int r = 0; r < RPL; ++r) {
        const int k = rl * RPL + r;
#pragma unroll
        for (int jv = 0; jv < 7; ++jv) {
          *(float4*)(wp + k * CHUNK_F + 4 * jv) =
              make_float4(A1[r][4 * jv + 0], A1[r][4 * jv + 1],
                          A1[r][4 * jv + 2], A1[r][4 * jv + 3]);
        }
      }
    }
  }
  __syncthreads();  // partials visible to readers

  // readers: slots 0 and 4 chain through their item's 3 partials.
  const int cbase = (slot >= 4) ? 3 * D : 0;
  {
    const float* Bs = &lds[0][0] + cbase + 0 * D;  // P1
    MATMUL(A1, A0);                                // A0 = P0 @ P1
  }
  {
    const float* Bs = &lds[0][0] + cbase + 1 * D;  // P2
    MATMUL(A0, A1);                                // A1 = (P0@P1) @ P2
  }
  {
    const float* Bs = &lds[0][0] + cbase + 2 * D;  // P3
    MATMUL(A1, A0);                                // A0 = ((P0@P1)@P2) @ P3
  }

  // store: only the reader slots (0 and 4) hold a finished item product.
  if (slot == 0 || slot == 4) {
    float* op = dst + (size_t)item * EMB;
#pragma unroll
    for (int r = 0; r < RPL; ++r) {
      float* rp = op + (rl * RPL + r) * D;
#pragma unroll
      for (int jv = 0; jv < 7; ++jv) {
        *(float4*)(rp + 4 * jv) =
            make_float4(A0[r][4 * jv + 0], A0[r][4 * jv + 1],
                        A0[r][4 * jv + 2], A0[r][4 * jv + 3]);
      }
    }
  }
}

extern "C" void kernel_launch(void* const* d_in, const int* in_sizes, int n_in,
                              void* d_out, int out_size, void* d_ws,
                              size_t ws_size, hipStream_t stream) {
  const float* table = (const float*)d_in[0];
  const int* sent = (const int*)d_in[1];
  float* out = (float*)d_out;

  // single fused dispatch: 8192 segment-tasks, 8 per block -> 1024 blocks
  const int ntask = NITEMS * 4;
  fused_kernel<<<ntask / SPW, 64, 0, stream>>>(table, sent, out, ntask);
}

// Round 8
// 1049.983 us; speedup vs baseline: 2.1107x; 2.1107x over previous
//
#include <hip/hip_runtime.h>
#include <stdint.h>

// Word2MatEncoder: out[b] = prod_{s=0..63} table[sent[b,s]]  (28x28 fp32 chain)
//
// R13: R12 falsified the asm-vs-builtin poison theory (builtin waitcnts still
// 256 VGPR + 2.2GB scratch). Clean split across all 8 experiments: kernels
// WITH __syncthreads in the compute loop are clean (R5/R10, 144-160 VGPR);
// ALL barrier-free pipelined variants spilled (R7/R8/R9/R11/R12, 256 VGPR).
// The barrier is the scheduling fence that keeps per-round liveness compact;
// without it the scheduler pipelines across rounds and regalloc dumps the
// two 112-float A-arrays to scratch each round (traffic matches). So:
// intra-wave DMA/compute overlap is off the table. Hide the stall with TLP.
// R10 is pinned at 1 wave/SIMD (grid 1024 = (16,4) cap) -- every ds_read
// latency + DMA drain cycle is exposed (VALUBusy 38%).
// Change: (8,8) decomposition. One block per item (8 segments of 8), grid
// 2048; 56-lane dma layout (CHUNK_F=224) shrinks LDS to 25088B -> 6
// blocks/CU = 1.5 waves/SIMD. Combine = 3-round binary tree (log2 8):
//   C1: odd slots publish P(2j+1); even slots A0 = A1 @ P  -> 4 products
//   C2: slots 2,6 publish;       slots 0,4 A1 = A0 @ P     -> 2 products
//   C3: slot 4 publishes;        slot 0  A0 = A1 @ P       -> item product
// Chain STEP/MATMUL/barrier structure is R10 VERBATIM (sync loop, single
// buffer, builtin vmcnt(0), dma-after-matmul, gn pointer chase) modulo
// CHUNK_F 256->224 (stride still 0 mod 32: conflict-free reads).
// fp32 throughout (no fp32 MFMA on CDNA4; bf16 error compounds over 63 muls).

#define D 28
#define EMB 784
#define SEQ 64
#define NITEMS 2048
#define LPI 7            // lanes per slot
#define SPW 8            // slots per wave (8 segments of one item)
#define RPL 4            // rows of the running product per lane
#define SEG_LEN 8
#define NCHUNK 28        // DMA chunks per matrix-set (1 row x 8 slots each)
#define CHUNK_F 224      // floats per chunk (56 lanes x 16B; lanes 56-63 off)
#define BUF_F (NCHUNK * CHUNK_F)  // 6272 floats = 25088 B

typedef __attribute__((address_space(3))) uint32_t lds_u32;
typedef const __attribute__((address_space(1))) uint32_t glb_u32;

// Stage one matrix per slot into LDS. glane = matrix base + rl*16B (per lane);
// chunk t pulls row t of each slot's matrix. Lanes 56-63 must be exec-masked
// off: with CHUNK_F=224 their HW write offset (lane*16B = 896..1008B) would
// land in the next chunk's slot-0 region. (R12 proved this predicate+layout
// numerically correct.)
__device__ __forceinline__ void dma_mat(const float* glane, float* lds0,
                                        int lane) {
  if (lane < SPW * LPI) {
#pragma unroll
    for (int t = 0; t < NCHUNK; ++t)
      __builtin_amdgcn_global_load_lds((glb_u32*)(glane + t * D),
                                       (lds_u32*)(lds0 + t * CHUNK_F), 16, 0,
                                       0);
  }
}

// Cc = Aa @ M   (M staged in LDS at Bs with the chunk layout) -- R10 verbatim
// modulo CHUNK_F. Read banks: (slot*28 + 4*jv) mod 32 distinct across the 8
// slots (28-stride walks 0,28,24,20,16,12,8,4) -- conflict-free.
#define MATMUL(Aa, Cc)                                                         \
  do {                                                                         \
    _Pragma("unroll") for (int k = 0; k < D; ++k) {                            \
      _Pragma("unroll") for (int jv = 0; jv < 7; ++jv) {                       \
        float4 m = *(const float4*)(Bs + k * CHUNK_F + 4 * jv);                \
        _Pragma("unroll") for (int r = 0; r < RPL; ++r) {                      \
          float a = Aa[r][k];                                                  \
          if (k == 0) {                                                        \
            Cc[r][4 * jv + 0] = a * m.x;                                       \
            Cc[r][4 * jv + 1] = a * m.y;                                       \
            Cc[r][4 * jv + 2] = a * m.z;                                       \
            Cc[r][4 * jv + 3] = a * m.w;                                       \
          } else {                                                             \
            Cc[r][4 * jv + 0] = fmaf(a, m.x, Cc[r][4 * jv + 0]);               \
            Cc[r][4 * jv + 1] = fmaf(a, m.y, Cc[r][4 * jv + 1]);               \
            Cc[r][4 * jv + 2] = fmaf(a, m.z, Cc[r][4 * jv + 2]);               \
            Cc[r][4 * jv + 3] = fmaf(a, m.w, Cc[r][4 * jv + 3]);               \
          }                                                                    \
        }                                                                      \
      }                                                                        \
    }                                                                          \
  } while (0)

// One chain step: wait staged matrix, multiply, then DMA the next one. -- R10.
#define STEP(Aa, Cc)                                                           \
  do {                                                                         \
    __builtin_amdgcn_s_waitcnt(0x0f70); /* vmcnt(0): matrix landed */          \
    __syncthreads();                                                           \
    MATMUL(Aa, Cc);                                                            \
    __syncthreads(); /* all LDS reads drained before overwrite */              \
    if (s + 1 < SEG_LEN) {                                                     \
      dma_mat(gn, lds, lane);                                                  \
      int nn = (s + 2 < SEG_LEN) ? s + 2 : SEG_LEN - 1;                        \
      gn = glane(nn);                                                          \
    }                                                                          \
    ++s;                                                                       \
  } while (0)

// Publish this slot's running product (array Aa) to LDS column col (floats),
// in the exact k*CHUNK_F+col+j layout MATMUL reads.
#define WRITE_P(Aa, col)                                                       \
  do {                                                                         \
    float* wp = lds + (col);                                                   \
    _Pragma("unroll") for (int r = 0; r < RPL; ++r) {                          \
      const int k = rl * RPL + r;                                              \
      _Pragma("unroll") for (int jv = 0; jv < 7; ++jv) {                       \
        *(float4*)(wp + k * CHUNK_F + 4 * jv) =                                \
            make_float4(Aa[r][4 * jv + 0], Aa[r][4 * jv + 1],                  \
                        Aa[r][4 * jv + 2], Aa[r][4 * jv + 3]);                 \
      }                                                                        \
    }                                                                          \
  } while (0)

// One block = one item (8 segments of 8). Chain 8 matrices per slot, then
// tree-combine the 8 segment products in-block and store the item product.
__global__ __launch_bounds__(64, 1) void fused_kernel(
    const float* __restrict__ src, const int* __restrict__ sent,
    float* __restrict__ dst) {
  __shared__ __align__(16) float lds[BUF_F];

  const int lane = threadIdx.x;
  int slot = lane / LPI;
  int rl = lane - slot * LPI;
  if (slot >= SPW) {  // lanes 56..63 mirror slot 7 (benign duplicates)
    slot = SPW - 1;
    rl = (lane - 56 < LPI) ? lane - 56 : LPI - 1;
  }
  const int item = blockIdx.x;        // grid = NITEMS
  const int* sp = sent + item * SEQ + slot * SEG_LEN;  // slot == segment

  auto glane = [&](int s) -> const float* {
    return src + (size_t)sp[s] * EMB + rl * 4;  // this lane's 16B row slice
  };

  float A0[RPL][D], A1[RPL][D];

  // A0 = this lane's rows (rl*4 .. rl*4+3) of the first matrix (direct loads)
  {
    const float* m0 = src + (size_t)sp[0] * EMB;
#pragma unroll
    for (int r = 0; r < RPL; ++r) {
      const float* rp = m0 + (rl * RPL + r) * D;
#pragma unroll
      for (int jv = 0; jv < 7; ++jv) {
        float4 v = *(const float4*)(rp + 4 * jv);
        A0[r][4 * jv + 0] = v.x;
        A0[r][4 * jv + 1] = v.y;
        A0[r][4 * jv + 2] = v.z;
        A0[r][4 * jv + 3] = v.w;
      }
    }
  }

  // stage matrix 1; prefetch pointer for matrix 2
  dma_mat(glane(1), lds, lane);
  const float* gn = glane(2);
  const float* Bs = lds + slot * (LPI * 4);  // slot*28 floats

  int s = 1;
#pragma unroll 1
  for (int p = 0; p < (SEG_LEN - 1) / 2; ++p) {
    STEP(A0, A1);
    STEP(A1, A0);
  }
  STEP(A0, A1);  // step 7 (odd count) -> segment product P_slot in A1

  // ---- tree combine: (((P0 P1)(P2 P3))((P4 P5)(P6 P7))) ----
  // C1: odd slots publish; even slots multiply.
  if (slot & 1) WRITE_P(A1, (slot >> 1) * D);
  __syncthreads();
  {
    const float* Bs = lds + (slot >> 1) * D;  // slot0->col0(P1), slot2->P3,...
    MATMUL(A1, A0);                           // A0 = P_even @ P_odd
  }
  __syncthreads();  // C1 reads drained before C2 overwrites cols 0/28

  // C2: slots 2,6 publish; slots 0,4 multiply.
  if (slot == 2 || slot == 6) WRITE_P(A0, (slot >> 2) * D);
  __syncthreads();
  {
    const float* Bs = lds + (slot >> 2) * D;  // slot0->col0, slot4->col28
    MATMUL(A0, A1);                           // A1 = (..)(..)
  }
  __syncthreads();  // C2 reads drained before C3 overwrites col 0

  // C3: slot 4 publishes; slot 0 multiplies.
  if (slot == 4) WRITE_P(A1, 0);
  __syncthreads();
  {
    const float* Bs = lds;
    MATMUL(A1, A0);  // A0 = full item product (valid in slot 0)
  }

  // store: slot 0 holds the finished item product.
  if (slot == 0) {
    float* op = dst + (size_t)item * EMB;
#pragma unroll
    for (int r = 0; r < RPL; ++r) {
      float* rp = op + (rl * RPL + r) * D;
#pragma unroll
      for (int jv = 0; jv < 7; ++jv) {
        *(float4*)(rp + 4 * jv) =
            make_float4(A0[r][4 * jv + 0], A0[r][4 * jv + 1],
                        A0[r][4 * jv + 2], A0[r][4 * jv + 3]);
      }
    }
  }
}

extern "C" void kernel_launch(void* const* d_in, const int* in_sizes, int n_in,
                              void* d_out, int out_size, void* d_ws,
                              size_t ws_size, hipStream_t stream) {
  const float* table = (const float*)d_in[0];
  const int* sent = (const int*)d_in[1];
  float* out = (float*)d_out;

  // one block per item: grid 2048, 64 threads, 25KB LDS -> 6 blocks/CU
  fused_kernel<<<NITEMS, 64, 0, stream>>>(table, sent, out);
}

// Round 9
// 499.311 us; speedup vs baseline: 4.4385x; 2.1029x over previous
//
#include <hip/hip_runtime.h>
#include <stdint.h>

// Word2MatEncoder: out[b] = prod_{s=0..63} table[sent[b,s]]  (28x28 fp32 chain)
//
// R14: nine-experiment ledger. Clean codegen (144-160 VGPR, no scratch):
// R5, R10 -- both use the UNCONDITIONAL 64-lane dma_mat with CHUNK_F=256.
// Spillers (256 VGPR or wholesale scratch demotion, GB-scale HBM traffic):
// R7/R11/R12/R13 (lane-predicated dma and/or CHUNK_F=224) and R8 (no
// global_load_lds, 5 register arrays). R13 falsified the "barrier in loop"
// theory (it had barriers and still spilled); the surviving discriminator is
// the DMA shape. Rule: the R5/R10 DMA+STEP machinery is untouchable.
// This round keeps R10's machinery VERBATIM and changes only the work
// decomposition, which is R10's real limiter: grid 1024 = 4 blocks/CU =
// 0.89 waves/SIMD (5 fit in LDS), so ~66% of wall is exposed latency with
// no co-resident wave to hide it.
//   (8,8): one block per item, 8 segments x 8 matrices, grid 2048 ->
//   5 blocks/CU resident, 1.25 waves/SIMD, and rounds/block 18 -> 10
//   (7 chain + 3 tree-combine). Tree (same association as R13, which
//   passed): C1 odd slots publish, even multiply; C2 slots 2/6 publish,
//   0/4 multiply; C3 slot 4 publishes, slot 0 multiplies; slot 0 stores.
// fp32 throughout (no fp32 MFMA on CDNA4; bf16 error compounds over 63 muls).

#define D 28
#define EMB 784
#define SEQ 64
#define NITEMS 2048
#define LPI 7            // lanes per slot
#define SPW 8            // slots per wave (8 segments of one item)
#define RPL 4            // rows of the running product per lane
#define SEG_LEN 8
#define NCHUNK 28        // DMA chunks per matrix-set (1 row x 9 lane-groups)
#define CHUNK_F 256      // floats per chunk (64 lanes x 16B) -- R10 layout
#define BUF_F (NCHUNK * CHUNK_F)  // 7168 floats = 28672 B

typedef __attribute__((address_space(3))) uint32_t lds_u32;
typedef const __attribute__((address_space(1))) uint32_t glb_u32;

// Stage one matrix per slot into LDS -- R5/R10 VERBATIM: unconditional, all
// 64 lanes (lanes 56-63 mirror slot 7 into floats 224..255, unused region).
__device__ __forceinline__ void dma_mat(const float* glane, float* lds0) {
#pragma unroll
  for (int t = 0; t < NCHUNK; ++t)
    __builtin_amdgcn_global_load_lds((glb_u32*)(glane + t * D),
                                     (lds_u32*)(lds0 + t * CHUNK_F), 16, 0, 0);
}

// Cc = Aa @ M   (M staged in LDS at Bs with the chunk layout) -- R10 verbatim.
#define MATMUL(Aa, Cc)                                                         \
  do {                                                                         \
    _Pragma("unroll") for (int k = 0; k < D; ++k) {                            \
      _Pragma("unroll") for (int jv = 0; jv < 7; ++jv) {                       \
        float4 m = *(const float4*)(Bs + k * CHUNK_F + 4 * jv);                \
        _Pragma("unroll") for (int r = 0; r < RPL; ++r) {                      \
          float a = Aa[r][k];                                                  \
          if (k == 0) {                                                        \
            Cc[r][4 * jv + 0] = a * m.x;                                       \
            Cc[r][4 * jv + 1] = a * m.y;                                       \
            Cc[r][4 * jv + 2] = a * m.z;                                       \
            Cc[r][4 * jv + 3] = a * m.w;                                       \
          } else {                                                             \
            Cc[r][4 * jv + 0] = fmaf(a, m.x, Cc[r][4 * jv + 0]);               \
            Cc[r][4 * jv + 1] = fmaf(a, m.y, Cc[r][4 * jv + 1]);               \
            Cc[r][4 * jv + 2] = fmaf(a, m.z, Cc[r][4 * jv + 2]);               \
            Cc[r][4 * jv + 3] = fmaf(a, m.w, Cc[r][4 * jv + 3]);               \
          }                                                                    \
        }                                                                      \
      }                                                                        \
    }                                                                          \
  } while (0)

// One chain step: wait staged matrix, multiply, then DMA the next. -- R10.
#define STEP(Aa, Cc)                                                           \
  do {                                                                         \
    __builtin_amdgcn_s_waitcnt(0x0f70); /* vmcnt(0): matrix landed */          \
    __syncthreads();                                                           \
    MATMUL(Aa, Cc);                                                            \
    __syncthreads(); /* all LDS reads drained before overwrite */              \
    if (s + 1 < SEG_LEN) {                                                     \
      dma_mat(gn, lds);                                                        \
      int nn = (s + 2 < SEG_LEN) ? s + 2 : SEG_LEN - 1;                        \
      gn = glane(nn);                                                          \
    }                                                                          \
    ++s;                                                                       \
  } while (0)

// Publish this slot's running product (array Aa) to LDS column col (floats),
// in the exact k*CHUNK_F+col+j layout MATMUL reads. -- R10's writer pattern.
#define WRITE_P(Aa, col)                                                       \
  do {                                                                         \
    float* wp = lds + (col);                                                   \
    _Pragma("unroll") for (int r = 0; r < RPL; ++r) {                          \
      const int k = rl * RPL + r;                                              \
      _Pragma("unroll") for (int jv = 0; jv < 7; ++jv) {                       \
        *(float4*)(wp + k * CHUNK_F + 4 * jv) =                                \
            make_float4(Aa[r][4 * jv + 0], Aa[r][4 * jv + 1],                  \
                        Aa[r][4 * jv + 2], Aa[r][4 * jv + 3]);                 \
      }                                                                        \
    }                                                                          \
  } while (0)

// One block = one item (8 segments of 8 matrices). Chain, then tree-combine.
__global__ __launch_bounds__(64, 1) void fused_kernel(
    const float* __restrict__ src, const int* __restrict__ sent,
    float* __restrict__ dst) {
  __shared__ __align__(16) float lds[BUF_F];

  const int lane = threadIdx.x;
  int slot = lane / LPI;
  int rl = lane - slot * LPI;
  if (slot >= SPW) {  // lanes 56..63 mirror slot 7 (benign duplicates) -- R10
    slot = SPW - 1;
    rl = (lane - 56 < LPI) ? lane - 56 : LPI - 1;
  }
  const int item = blockIdx.x;  // grid = NITEMS
  const int* sp = sent + item * SEQ + slot * SEG_LEN;  // slot == segment

  auto glane = [&](int s) -> const float* {
    return src + (size_t)sp[s] * EMB + rl * 4;  // this lane's 16B row slice
  };

  float A0[RPL][D], A1[RPL][D];

  // A0 = this lane's rows (rl*4 .. rl*4+3) of the first matrix -- R10.
  {
    const float* m0 = src + (size_t)sp[0] * EMB;
#pragma unroll
    for (int r = 0; r < RPL; ++r) {
      const float* rp = m0 + (rl * RPL + r) * D;
#pragma unroll
      for (int jv = 0; jv < 7; ++jv) {
        float4 v = *(const float4*)(rp + 4 * jv);
        A0[r][4 * jv + 0] = v.x;
        A0[r][4 * jv + 1] = v.y;
        A0[r][4 * jv + 2] = v.z;
        A0[r][4 * jv + 3] = v.w;
      }
    }
  }

  // stage matrix 1; prefetch pointer for matrix 2 -- R10.
  dma_mat(glane(1), lds);
  const float* gn = glane(2);
  const float* Bs = lds + slot * (LPI * 4);  // slot*28 floats

  int s = 1;
#pragma unroll 1
  for (int p = 0; p < (SEG_LEN - 1) / 2; ++p) {
    STEP(A0, A1);
    STEP(A1, A0);
  }
  STEP(A0, A1);  // step 7 (odd count) -> segment product P_slot in A1

  // ---- tree combine: (((P0 P1)(P2 P3))((P4 P5)(P6 P7))) ----
  // (last STEP's trailing barrier already drained all chain LDS reads)
  // C1: odd slots publish P(2j+1) to col j*28; even slots multiply.
  if (slot & 1) WRITE_P(A1, (slot >> 1) * D);
  __syncthreads();
  {
    const float* Bs = lds + (slot >> 1) * D;  // slots 0/1->col0, 2/3->28, ...
    MATMUL(A1, A0);                           // A0 = P_even @ P_odd
  }
  __syncthreads();  // C1 reads drained before C2 overwrites cols 0/28

  // C2: slots 2,6 publish; slots 0,4 multiply.
  if (slot == 2 || slot == 6) WRITE_P(A0, (slot >> 2) * D);
  __syncthreads();
  {
    const float* Bs = lds + (slot >> 2) * D;  // slot0->col0, slot4->col28
    MATMUL(A0, A1);                           // A1 = quarter-products joined
  }
  __syncthreads();  // C2 reads drained before C3 overwrites col 0

  // C3: slot 4 publishes; slot 0 multiplies.
  if (slot == 4) WRITE_P(A1, 0);
  __syncthreads();
  {
    const float* Bs = lds;
    MATMUL(A1, A0);  // A0 = full item product (valid in slot 0)
  }

  // store: slot 0 holds the finished item product.
  if (slot == 0) {
    float* op = dst + (size_t)item * EMB;
#pragma unroll
    for (int r = 0; r < RPL; ++r) {
      float* rp = op + (rl * RPL + r) * D;
#pragma unroll
      for (int jv = 0; jv < 7; ++jv) {
        *(float4*)(rp + 4 * jv) =
            make_float4(A0[r][4 * jv + 0], A0[r][4 * jv + 1],
                        A0[r][4 * jv + 2], A0[r][4 * jv + 3]);
      }
    }
  }
}

extern "C" void kernel_launch(void* const* d_in, const int* in_sizes, int n_in,
                              void* d_out, int out_size, void* d_ws,
                              size_t ws_size, hipStream_t stream) {
  const float* table = (const float*)d_in[0];
  const int* sent = (const int*)d_in[1];
  float* out = (float*)d_out;

  // one block per item: grid 2048, 64 threads, 28KB LDS -> 5 blocks/CU
  fused_kernel<<<NITEMS, 64, 0, stream>>>(table, sent, out);
}